// Round 1
// 154.657 us; speedup vs baseline: 1.0692x; 1.0692x over previous
//
#include <hip/hip_runtime.h>
#include <stdint.h>

#define S_LEN 4096
#define EMB   1024
#define HEAD  64

typedef short bf16x8 __attribute__((ext_vector_type(8)));
typedef float f32x4  __attribute__((ext_vector_type(4)));
typedef float f32x16 __attribute__((ext_vector_type(16)));

// scale = 1/sqrt(64) = 0.125, folded with log2(e) so softmax uses exp2
#define QSCALE 0.18033688011112042f

__device__ __forceinline__ unsigned short f2bf(float f) {
    union { float f; uint32_t u; } v; v.f = f;
    uint32_t r = v.u + 0x7fffu + ((v.u >> 16) & 1u);
    return (unsigned short)(r >> 16);
}

// pack two f32 -> one u32 of 2x bf16 (RNE), gfx950 HW op (no builtin)
__device__ __forceinline__ int cvtpk_bf16(float lo, float hi_) {
    int r;
    asm("v_cvt_pk_bf16_f32 %0, %1, %2" : "=v"(r) : "v"(lo), "v"(hi_));
    return r;
}

// ---------------------------------------------------------------------------
// Kernel 0: W prep.  wt[m][n][k] = bf16(W_m[k][n]).  Coalesced via LDS
// transpose: 48 blocks = 3 mats x 16 k-chunks of 64.
// ---------------------------------------------------------------------------
__global__ void wprep_kernel(const float* __restrict__ Wq,
                             const float* __restrict__ Wk,
                             const float* __restrict__ Wv,
                             unsigned short* __restrict__ wt) {
    __shared__ float t[64][65];
    const int tid = threadIdx.x;
    const int m   = blockIdx.x >> 4;
    const int k0  = (blockIdx.x & 15) << 6;
    const float* W = (m == 0) ? Wq : (m == 1) ? Wk : Wv;
    for (int i = 0; i < 4; ++i) {
        const int k  = (tid >> 4) + i * 16;
        const int n4 = (tid & 15) << 2;
        float4 v = *(const float4*)&W[(k0 + k) * 64 + n4];
        t[k][n4 + 0] = v.x; t[k][n4 + 1] = v.y;
        t[k][n4 + 2] = v.z; t[k][n4 + 3] = v.w;
    }
    __syncthreads();
    const int n = tid >> 2, kq = (tid & 3) << 4;
    __align__(16) unsigned short u[16];
    for (int i = 0; i < 16; ++i) u[i] = f2bf(t[kq + i][n]);
    *(int4*)&wt[(m * 64 + n) * 1024 + k0 + kq]     = *(int4*)&u[0];
    *(int4*)&wt[(m * 64 + n) * 1024 + k0 + kq + 8] = *(int4*)&u[8];
}

// ---------------------------------------------------------------------------
// Kernel 1: fused QKV projection, bf16 MFMA GEMM, double-buffered LDS.
//   M=16384 rows, K=1024, N=192.  512 blocks x 32-row tiles, 512 thr,
//   BK=64 (16 iters).  LDS 63 KB -> 2 blocks/CU; launch_bounds(512,2)
//   gives the 128-VGPR cap that matches (NOT (512,4): that caps at 64
//   and forces scratch spills -- R7 lesson).
// ---------------------------------------------------------------------------
__global__ __launch_bounds__(512, 2) void qkv_kernel(
    const float* __restrict__ x, const unsigned short* __restrict__ wt,
    const float* __restrict__ bq, const float* __restrict__ bk,
    const float* __restrict__ bv,
    unsigned short* __restrict__ Qp, unsigned short* __restrict__ Kp,
    unsigned short* __restrict__ Vt) {

    __shared__ __align__(16) unsigned short xs[2][32 * 72];   // 9.2 KB
    __shared__ __align__(16) unsigned short ws[2][192 * 72];  // 55.3 KB

    const int tid  = threadIdx.x;
    const int lane = tid & 63;
    const int w    = tid >> 6;        // 0..7
    const int wm   = w & 1;           // 0..1  (16-row half)
    const int wn   = w >> 1;          // 0..3  (48-col strip)
    const int quad = lane >> 4;
    const int lid  = lane & 15;
    const int row0 = blockIdx.x * 32;

    f32x4 acc[3];
    for (int j = 0; j < 3; ++j) acc[j] = (f32x4){0.f, 0.f, 0.f, 0.f};

#define STAGE(BUF, K0)                                                         \
    do {                                                                       \
        {   /* x: 32 rows x 64 k fp32 -> bf16, one float4 per thread */        \
            int r = tid >> 4, c4 = (tid & 15) << 2;                            \
            float4 v = *(const float4*)&x[(row0 + r) * EMB + (K0) + c4];       \
            ushort4 u;                                                         \
            u.x = f2bf(v.x); u.y = f2bf(v.y); u.z = f2bf(v.z); u.w = f2bf(v.w);\
            *(ushort4*)&xs[BUF][r * 72 + c4] = u;                              \
        }                                                                      \
        for (int i = 0; i < 3; ++i) {  /* wt: 192 n x 64 k, 3 x b128/thr */    \
            int f = tid + i * 512;                                             \
            int n = f >> 3, kq = (f & 7) << 3;                                 \
            *(int4*)&ws[BUF][n * 72 + kq] =                                    \
                *(const int4*)&wt[(n << 10) + (K0) + kq];                      \
        }                                                                      \
    } while (0)

    STAGE(0, 0);
    __syncthreads();

    for (int kc = 0; kc < 16; ++kc) {
        const int cur = kc & 1;
        if (kc + 1 < 16) STAGE(cur ^ 1, (kc + 1) * 64);
        for (int kk = 0; kk < 2; ++kk) {
            bf16x8 a = *(const bf16x8*)&xs[cur][(wm * 16 + lid) * 72 + kk * 32 + quad * 8];
            for (int nt = 0; nt < 3; ++nt) {
                bf16x8 bfr = *(const bf16x8*)&ws[cur][(wn * 48 + nt * 16 + lid) * 72 + kk * 32 + quad * 8];
                acc[nt] = __builtin_amdgcn_mfma_f32_16x16x32_bf16(a, bfr, acc[nt], 0, 0, 0);
            }
        }
        __syncthreads();
    }
#undef STAGE

    for (int nt = 0; nt < 3; ++nt) {
        const int col = wn * 48 + nt * 16 + lid;
        const int mid = col >> 6;          // 0=Q 1=K 2=V, uniform per (wn,nt)
        const int lc  = col & 63;
        const float bias = (mid == 0) ? bq[lc] : (mid == 1) ? bk[lc] : bv[lc];
        const int rb = row0 + wm * 16 + quad * 4;   // + j
        f32x4 v = acc[nt];
        if (mid == 0) {
            for (int j = 0; j < 4; ++j)
                Qp[(rb + j) * 64 + lc] = f2bf((v[j] + bias) * QSCALE);
        } else if (mid == 1) {
            for (int j = 0; j < 4; ++j)
                Kp[(rb + j) * 64 + lc] = f2bf(v[j] + bias);
        } else {
            const int bb = rb >> 12, s = rb & 4095;  // rb%4==0 -> no straddle
            ushort4 u;
            u.x = f2bf(v[0] + bias); u.y = f2bf(v[1] + bias);
            u.z = f2bf(v[2] + bias); u.w = f2bf(v[3] + bias);
            *(ushort4*)&Vt[(bb * 64 + lc) * S_LEN + s] = u;
        }
    }
}

// ---------------------------------------------------------------------------
// Kernel 2: MFMA flash attention (causal) -- swapped-QK^T 32x32 structure.
//   S^T = mfma_32x32x16(K, Q): each lane holds P values for ONE q-row
//   (q = lane&31), keys spread over the 16 C-regs + lane-half.  Softmax is
//   fully in-register (exp2 on C-regs, lane-local row-sum), and the PV
//   A-fragment is rebuilt with v_cvt_pk_bf16_f32 + permlane32_swap (T12,
//   HK pattern) -- the old P->LDS->bf16-frag round-trip (32 ds_write +
//   lgkmcnt(0) drain + 4 ds_read_b128 + 128 f2bf VALU per tile) is gone.
//   32-key tiles keep VGPR peak ~= old kernel (no residency loss) and
//   remove the fully-masked half-tile on even q-tiles.
//   Mapping / 8-wave k-split / combine identical to R7.
// ---------------------------------------------------------------------------
__global__ __launch_bounds__(512, 2) void flash_kernel(
    const unsigned short* __restrict__ Qp, const unsigned short* __restrict__ Kp,
    const unsigned short* __restrict__ Vt, float* __restrict__ out) {

    __shared__ __align__(16) float Obuf[8][32][66];   // 67.6 KB
    __shared__ float lbuf[8][32];                     // 1 KB

    const int tid  = threadIdx.x;
    const int lane = tid & 63;
    const int w    = tid >> 6;        // 0..7 (k-split index)
    const int hi   = lane >> 5;       // lane half (0/1)
    const int l5   = lane & 31;       // q-row within tile / d within half

    // balanced (XCD, CU, slot) -> (batch, qt) mapping (unchanged)
    const int l  = blockIdx.x;        // 0..511
    const int x  = l & 7;             // XCD
    const int m  = l >> 3;            // arrival index within XCD, 0..63
    const int j  = m & 31;            // CU within XCD
    const int r  = m >> 5;            // resident slot 0/1
    const int b  = x & 3;             // batch -> XCDs {b, b+4}
    const int h  = x >> 2;
    const int qt = (h == 0) ? (r ? j : 127 - j)
                            : (r ? 32 + j : 95 - j);
    const int q0 = qt * 32;
    const int nt = qt + 1;            // 32-wide k tiles

    // Q as B-frags (regs whole kernel): B[d][q], lane holds Q[q=l5][d-chunk]
    bf16x8 qf[4];
#pragma unroll
    for (int dk = 0; dk < 4; ++dk)
        qf[dk] = *(const bf16x8*)&Qp[(b * S_LEN + q0 + l5) * 64 + dk * 16 + hi * 8];

    f32x16 O0 = {}, O1 = {};          // O[q][d], d-halves 0..31 / 32..63
    float ls = 0.f;                   // row-sum partial (q = l5, own key-half)

    const unsigned short* Kb = &Kp[b * S_LEN * 64];
    const unsigned short* Vb = &Vt[b * 64 * S_LEN];

    // prologue: K A-frags for first tile.  A[key][d]: lane holds K[key=l5][d-chunk]
    int t = w;
    bf16x8 kf[4];
    if (t < nt) {
#pragma unroll
        for (int dk = 0; dk < 4; ++dk)
            kf[dk] = *(const bf16x8*)&Kb[(t * 32 + l5) * 64 + dk * 16 + hi * 8];
    }

    while (t < nt) {
        const int kt = t << 5;
        // ---- V B-frags for this tile: B[key][d], 2 d-halves x 2 key-chunks
        bf16x8 vf[2][2];
#pragma unroll
        for (int dh = 0; dh < 2; ++dh)
#pragma unroll
            for (int kc = 0; kc < 2; ++kc)
                vf[dh][kc] = *(const bf16x8*)&Vb[(dh * 32 + l5) * S_LEN + kt + kc * 16 + hi * 8];

        // ---- swapped QK^T: st[rr] = S^T[key][q],
        //      key = kt + (rr&3) + 8*(rr>>2) + 4*hi,  q = q0 + l5
        __builtin_amdgcn_s_setprio(1);
        f32x16 st = {};
#pragma unroll
        for (int dk = 0; dk < 4; ++dk)
            st = __builtin_amdgcn_mfma_f32_32x32x16_bf16(kf[dk], qf[dk], st, 0, 0, 0);
        __builtin_amdgcn_s_setprio(0);

        // ---- prefetch K(t+8) (hidden under softmax + PV)
        const int tn = t + 8;
        if (tn < nt) {
#pragma unroll
            for (int dk = 0; dk < 4; ++dk)
                kf[dk] = *(const bf16x8*)&Kb[(tn * 32 + l5) * 64 + dk * 16 + hi * 8];
        }

        // ---- causal mask (diagonal tile only)
        if (t == nt - 1) {
#pragma unroll
            for (int rr = 0; rr < 16; ++rr) {
                const int key = kt + (rr & 3) + 8 * (rr >> 2) + 4 * hi;
                if (key > q0 + l5) st[rr] = -1e30f;
            }
        }

        // ---- exp2 + in-register P->bf16 A-frag, fused with PV.
        //  PV A-frag chunk kc needs P[q=l5][key = kc*16 + hi*8 + e]; its
        //  source C-reg is (e&3) + 8*kc + 4*hi in lane-half (e>>2).
        //  packs: p0=(r0,r1) p1=(r2,r3) [target hi=0], p2=(r4,r5) p3=(r6,r7)
        //  [target hi=1]; permlane32_swap(p0,p2) -> (w0,w2), (p1,p3) -> (w1,w3).
#pragma unroll
        for (int kc = 0; kc < 2; ++kc) {
            const int c8 = kc * 8;
            float ev[8];
#pragma unroll
            for (int i = 0; i < 8; ++i) ev[i] = exp2f(st[c8 + i]);
            ls += ((ev[0] + ev[1]) + (ev[2] + ev[3])) +
                  ((ev[4] + ev[5]) + (ev[6] + ev[7]));
            const int p0 = cvtpk_bf16(ev[0], ev[1]);
            const int p1 = cvtpk_bf16(ev[2], ev[3]);
            const int p2 = cvtpk_bf16(ev[4], ev[5]);
            const int p3 = cvtpk_bf16(ev[6], ev[7]);
            auto s02 = __builtin_amdgcn_permlane32_swap(p0, p2, false, false);
            auto s13 = __builtin_amdgcn_permlane32_swap(p1, p3, false, false);
            union { int wd[4]; bf16x8 v; } pf;
            pf.wd[0] = s02[0]; pf.wd[1] = s13[0];
            pf.wd[2] = s02[1]; pf.wd[3] = s13[1];
            __builtin_amdgcn_s_setprio(1);
            O0 = __builtin_amdgcn_mfma_f32_32x32x16_bf16(pf.v, vf[0][kc], O0, 0, 0, 0);
            O1 = __builtin_amdgcn_mfma_f32_32x32x16_bf16(pf.v, vf[1][kc], O1, 0, 0, 0);
            __builtin_amdgcn_s_setprio(0);
        }
        t = tn;
    }

    // ---- publish per-wave partials.  O C-layout: row(q) = (rr&3)+8*(rr>>2)+4*hi,
    //      col(d) = l5 (+32 for O1).  Row-sum: lane-halves hold complementary
    //      key-halves for the same q -> one shfl_xor(32).
    const float lt = ls + __shfl_xor(ls, 32);
#pragma unroll
    for (int rr = 0; rr < 16; ++rr) {
        const int row = (rr & 3) + 8 * (rr >> 2) + 4 * hi;
        Obuf[w][row][l5]      = O0[rr];
        Obuf[w][row][32 + l5] = O1[rr];
    }
    if (lane < 32) lbuf[w][l5] = lt;
    __syncthreads();

    // ---- combine: plain sums over 8 k-split partials; coalesced store
    const int col = tid & 63;
    const int r0  = tid >> 6;
    for (int ii = 0; ii < 4; ++ii) {
        const int row = r0 + ii * 8;
        float o = 0.f, lsum = 0.f;
        for (int ww = 0; ww < 8; ++ww) {
            o    += Obuf[ww][row][col];
            lsum += lbuf[ww][row];
        }
        out[(b * S_LEN + q0 + row) * 64 + col] = o / lsum;
    }
}

// ---------------------------------------------------------------------------
extern "C" void kernel_launch(void* const* d_in, const int* in_sizes, int n_in,
                              void* d_out, int out_size, void* d_ws, size_t ws_size,
                              hipStream_t stream) {
    const float* x  = (const float*)d_in[0];
    const float* Wq = (const float*)d_in[1];
    const float* bq = (const float*)d_in[2];
    const float* Wk = (const float*)d_in[3];
    const float* bk = (const float*)d_in[4];
    const float* Wv = (const float*)d_in[5];
    const float* bv = (const float*)d_in[6];
    float* out = (float*)d_out;

    unsigned short* wt = (unsigned short*)d_ws;   // 3*64*1024
    unsigned short* Qp = wt + 196608;             // 16384*64 each
    unsigned short* Kp = Qp + 1048576;
    unsigned short* Vt = Kp + 1048576;            // [b][64][4096]

    hipLaunchKernelGGL(wprep_kernel, dim3(48), dim3(256), 0, stream, Wq, Wk, Wv, wt);
    hipLaunchKernelGGL(qkv_kernel, dim3(512), dim3(512), 0, stream,
                       x, wt, bq, bk, bv, Qp, Kp, Vt);
    hipLaunchKernelGGL(flash_kernel, dim3(512), dim3(512), 0, stream,
                       Qp, Kp, Vt, out);
}

// Round 2
// 153.169 us; speedup vs baseline: 1.0796x; 1.0097x over previous
//
#include <hip/hip_runtime.h>
#include <stdint.h>

#define S_LEN 4096
#define EMB   1024
#define HEAD  64

typedef short bf16x8 __attribute__((ext_vector_type(8)));
typedef float f32x4  __attribute__((ext_vector_type(4)));
typedef float f32x16 __attribute__((ext_vector_type(16)));
typedef unsigned short ushort8 __attribute__((ext_vector_type(8)));

// scale = 1/sqrt(64) = 0.125, folded with log2(e) so softmax uses exp2
#define QSCALE 0.18033688011112042f

__device__ __forceinline__ unsigned short f2bf(float f) {
    union { float f; uint32_t u; } v; v.f = f;
    uint32_t r = v.u + 0x7fffu + ((v.u >> 16) & 1u);
    return (unsigned short)(r >> 16);
}

// pack two f32 -> one u32 of 2x bf16 (RNE), gfx950 HW op (no builtin)
__device__ __forceinline__ int cvtpk_bf16(float lo, float hi_) {
    int r;
    asm("v_cvt_pk_bf16_f32 %0, %1, %2" : "=v"(r) : "v"(lo), "v"(hi_));
    return r;
}

// async global->LDS, 16B per lane.  LDS dest is wave-uniform base + lane*16;
// global src is per-lane (m104).  size must be a literal.
__device__ __forceinline__ void gload_lds16(const void* g, void* l) {
    __builtin_amdgcn_global_load_lds(
        (const __attribute__((address_space(1))) void*)g,
        (__attribute__((address_space(3))) void*)l, 16, 0, 0);
}

// ---------------------------------------------------------------------------
// Kernel 0: W prep.  Writes wt as 16 per-kchunk LINEAR LDS IMAGES of
// 192 rows x 128 B, XOR-swizzled (chunk ^= row&7 on 16B chunks) so qkv can
// stage it with global_load_lds (linear dest) and read with swizzled
// ds_read_b128 conflict-free (rule #21: pre-swizzled source + swizzled read).
//   wt[kc*12288 + n_img*64 + ((c8 ^ (n&7))*8 + k&7)]   (shorts)
// 48 blocks = 3 mats x 16 k-chunks of 64.
// ---------------------------------------------------------------------------
__global__ void wprep_kernel(const float* __restrict__ Wq,
                             const float* __restrict__ Wk,
                             const float* __restrict__ Wv,
                             unsigned short* __restrict__ wt) {
    __shared__ float t[64][65];
    const int tid = threadIdx.x;
    const int m   = blockIdx.x >> 4;
    const int kcb = blockIdx.x & 15;
    const int k0  = kcb << 6;
    const float* W = (m == 0) ? Wq : (m == 1) ? Wk : Wv;
    for (int i = 0; i < 4; ++i) {
        const int k  = (tid >> 4) + i * 16;
        const int n4 = (tid & 15) << 2;
        float4 v = *(const float4*)&W[(k0 + k) * 64 + n4];
        t[k][n4 + 0] = v.x; t[k][n4 + 1] = v.y;
        t[k][n4 + 2] = v.z; t[k][n4 + 3] = v.w;
    }
    __syncthreads();
    const int n = tid >> 2, kq = (tid & 3) << 4;   // 16 k-values per thread
    __align__(16) unsigned short u[16];
    for (int i = 0; i < 16; ++i) u[i] = f2bf(t[kq + i][n]);
    const int nimg = m * 64 + n;
    const int base = kcb * 12288 + nimg * 64;      // shorts
    const int c0   = (kq >> 3) ^ (n & 7);          // swizzled 16B-chunk idx
    const int c1   = ((kq >> 3) + 1) ^ (n & 7);
    *(int4*)&wt[base + c0 * 8] = *(int4*)&u[0];
    *(int4*)&wt[base + c1 * 8] = *(int4*)&u[8];
}

// ---------------------------------------------------------------------------
// Kernel 1: fused QKV projection, bf16 MFMA GEMM.
//   M=16384, K=1024, N=192.  256 blocks x 64-row tiles, 512 thr, BK=64.
//   W tile staged via global_load_lds (16B) from the pre-swizzled wt image
//   (no VGPR round-trip); x tile reg-staged with fp32->bf16 convert into a
//   72-padded buffer (144B row stride: 16B-aligned, ~2-way banks = free).
//   vs the old 32-row version: half the W L2 traffic, half the barriers,
//   half the per-output staging VALU.
// ---------------------------------------------------------------------------
__global__ __launch_bounds__(512, 2) void qkv_kernel(
    const float* __restrict__ x, const unsigned short* __restrict__ wt,
    const float* __restrict__ bq, const float* __restrict__ bk,
    const float* __restrict__ bv,
    unsigned short* __restrict__ Qp, unsigned short* __restrict__ Kp,
    unsigned short* __restrict__ Vt) {

    __shared__ __align__(16) unsigned short xs[2][64 * 72];   // 18.4 KB
    __shared__ __align__(16) unsigned short ws[2][12288];     // 49.2 KB

    const int tid  = threadIdx.x;
    const int lane = tid & 63;
    const int w    = tid >> 6;        // 0..7
    const int wm   = w & 3;           // 0..3  (16-row quarter)
    const int wn   = w >> 2;          // 0..1  (96-col half)
    const int quad = lane >> 4;
    const int lid  = lane & 15;
    const int row0 = blockIdx.x * 64;

    f32x4 acc[6];
    for (int j = 0; j < 6; ++j) acc[j] = (f32x4){0.f, 0.f, 0.f, 0.f};

#define STAGE(BUF, KC)                                                         \
    do {                                                                       \
        {   /* x: 64 rows x 64 k fp32 -> bf16, 8 floats per thread */          \
            int rr = tid >> 3, c8 = (tid & 7) << 3;                            \
            const float* xp = &x[(row0 + rr) * EMB + (KC) * 64 + c8];          \
            float4 v0 = *(const float4*)xp;                                    \
            float4 v1 = *(const float4*)(xp + 4);                              \
            ushort8 u;                                                         \
            u[0] = f2bf(v0.x); u[1] = f2bf(v0.y);                              \
            u[2] = f2bf(v0.z); u[3] = f2bf(v0.w);                              \
            u[4] = f2bf(v1.x); u[5] = f2bf(v1.y);                              \
            u[6] = f2bf(v1.z); u[7] = f2bf(v1.w);                              \
            *(ushort8*)&xs[BUF][rr * 72 + c8] = u;                             \
        }                                                                      \
        {   /* wt chunk: 24.6 KB linear swizzled image, 3 KB per wave */       \
            const unsigned short* gs = &wt[(KC) * 12288 + w * 1536 + lane * 8];\
            gload_lds16(gs,        &ws[BUF][w * 1536]);                        \
            gload_lds16(gs +  512, &ws[BUF][w * 1536 +  512]);                 \
            gload_lds16(gs + 1024, &ws[BUF][w * 1536 + 1024]);                 \
        }                                                                      \
    } while (0)

    STAGE(0, 0);
    __syncthreads();

    for (int kc = 0; kc < 16; ++kc) {
        const int cur = kc & 1;
        if (kc + 1 < 16) STAGE(cur ^ 1, kc + 1);
        for (int kk = 0; kk < 2; ++kk) {
            bf16x8 a = *(const bf16x8*)&xs[cur][(wm * 16 + lid) * 72 + kk * 32 + quad * 8];
            const int swz = ((((kk << 2) | quad) ^ (lid & 7)) << 3);
            for (int nt = 0; nt < 6; ++nt) {
                const int n = wn * 96 + nt * 16 + lid;
                bf16x8 bfr = *(const bf16x8*)&ws[cur][n * 64 + swz];
                acc[nt] = __builtin_amdgcn_mfma_f32_16x16x32_bf16(a, bfr, acc[nt], 0, 0, 0);
            }
        }
        __syncthreads();
    }
#undef STAGE

    for (int nt = 0; nt < 6; ++nt) {
        const int col = wn * 96 + nt * 16 + lid;
        const int mid = col >> 6;          // 0=Q 1=K 2=V, uniform per (wn,nt)
        const int lc  = col & 63;
        const float bias = (mid == 0) ? bq[lc] : (mid == 1) ? bk[lc] : bv[lc];
        const int rb = row0 + wm * 16 + quad * 4;   // + j
        f32x4 v = acc[nt];
        if (mid == 0) {
            for (int j = 0; j < 4; ++j)
                Qp[(rb + j) * 64 + lc] = f2bf((v[j] + bias) * QSCALE);
        } else if (mid == 1) {
            for (int j = 0; j < 4; ++j)
                Kp[(rb + j) * 64 + lc] = f2bf(v[j] + bias);
        } else {
            const int bb = rb >> 12, s = rb & 4095;  // rb%4==0 -> no straddle
            ushort4 u;
            u.x = f2bf(v[0] + bias); u.y = f2bf(v[1] + bias);
            u.z = f2bf(v[2] + bias); u.w = f2bf(v[3] + bias);
            *(ushort4*)&Vt[(bb * 64 + lc) * S_LEN + s] = u;
        }
    }
}

// ---------------------------------------------------------------------------
// Kernel 2: MFMA flash attention (causal) -- swapped-QK^T 32x32 structure.
//   Softmax fully in-register (swapped operands make the key axis lane-local),
//   P->bf16 A-frags via v_cvt_pk_bf16_f32 + permlane32_swap (T12).
//   This round: exp2f -> __builtin_amdgcn_exp2f (raw v_exp_f32).  OCML's
//   exp2f carries a ~6-instr denorm-range fixup per call; with fixed-max
//   softmax the raw op is exact where it matters (masked -1e30 -> 0, denormal
//   P ~ 0), cutting per-tile softmax VALU ~4x.
// ---------------------------------------------------------------------------
__global__ __launch_bounds__(512, 2) void flash_kernel(
    const unsigned short* __restrict__ Qp, const unsigned short* __restrict__ Kp,
    const unsigned short* __restrict__ Vt, float* __restrict__ out) {

    __shared__ __align__(16) float Obuf[8][32][66];   // 67.6 KB
    __shared__ float lbuf[8][32];                     // 1 KB

    const int tid  = threadIdx.x;
    const int lane = tid & 63;
    const int w    = tid >> 6;        // 0..7 (k-split index)
    const int hi   = lane >> 5;       // lane half (0/1)
    const int l5   = lane & 31;       // q-row within tile / d within half

    // balanced (XCD, CU, slot) -> (batch, qt) mapping (unchanged)
    const int l  = blockIdx.x;        // 0..511
    const int x  = l & 7;             // XCD
    const int m  = l >> 3;            // arrival index within XCD, 0..63
    const int j  = m & 31;            // CU within XCD
    const int r  = m >> 5;            // resident slot 0/1
    const int b  = x & 3;             // batch -> XCDs {b, b+4}
    const int h  = x >> 2;
    const int qt = (h == 0) ? (r ? j : 127 - j)
                            : (r ? 32 + j : 95 - j);
    const int q0 = qt * 32;
    const int nt = qt + 1;            // 32-wide k tiles

    // Q as B-frags (regs whole kernel): B[d][q], lane holds Q[q=l5][d-chunk]
    bf16x8 qf[4];
#pragma unroll
    for (int dk = 0; dk < 4; ++dk)
        qf[dk] = *(const bf16x8*)&Qp[(b * S_LEN + q0 + l5) * 64 + dk * 16 + hi * 8];

    f32x16 O0 = {}, O1 = {};          // O[q][d], d-halves 0..31 / 32..63
    float ls = 0.f;                   // row-sum partial (q = l5, own key-half)

    const unsigned short* Kb = &Kp[b * S_LEN * 64];
    const unsigned short* Vb = &Vt[b * 64 * S_LEN];

    // prologue: K A-frags for first tile.  A[key][d]: lane holds K[key=l5][d-chunk]
    int t = w;
    bf16x8 kf[4];
    if (t < nt) {
#pragma unroll
        for (int dk = 0; dk < 4; ++dk)
            kf[dk] = *(const bf16x8*)&Kb[(t * 32 + l5) * 64 + dk * 16 + hi * 8];
    }

    while (t < nt) {
        const int kt = t << 5;
        // ---- V B-frags for this tile: B[key][d], 2 d-halves x 2 key-chunks
        bf16x8 vf[2][2];
#pragma unroll
        for (int dh = 0; dh < 2; ++dh)
#pragma unroll
            for (int kc = 0; kc < 2; ++kc)
                vf[dh][kc] = *(const bf16x8*)&Vb[(dh * 32 + l5) * S_LEN + kt + kc * 16 + hi * 8];

        // ---- swapped QK^T: st[rr] = S^T[key][q],
        //      key = kt + (rr&3) + 8*(rr>>2) + 4*hi,  q = q0 + l5
        __builtin_amdgcn_s_setprio(1);
        f32x16 st = {};
#pragma unroll
        for (int dk = 0; dk < 4; ++dk)
            st = __builtin_amdgcn_mfma_f32_32x32x16_bf16(kf[dk], qf[dk], st, 0, 0, 0);
        __builtin_amdgcn_s_setprio(0);

        // ---- prefetch K(t+8) (hidden under softmax + PV)
        const int tn = t + 8;
        if (tn < nt) {
#pragma unroll
            for (int dk = 0; dk < 4; ++dk)
                kf[dk] = *(const bf16x8*)&Kb[(tn * 32 + l5) * 64 + dk * 16 + hi * 8];
        }

        // ---- causal mask (diagonal tile only)
        if (t == nt - 1) {
#pragma unroll
            for (int rr = 0; rr < 16; ++rr) {
                const int key = kt + (rr & 3) + 8 * (rr >> 2) + 4 * hi;
                if (key > q0 + l5) st[rr] = -1e30f;
            }
        }

        // ---- exp2 + in-register P->bf16 A-frag, fused with PV.
#pragma unroll
        for (int kc = 0; kc < 2; ++kc) {
            const int c8 = kc * 8;
            float ev[8];
#pragma unroll
            for (int i = 0; i < 8; ++i) ev[i] = __builtin_amdgcn_exp2f(st[c8 + i]);
            ls += ((ev[0] + ev[1]) + (ev[2] + ev[3])) +
                  ((ev[4] + ev[5]) + (ev[6] + ev[7]));
            const int p0 = cvtpk_bf16(ev[0], ev[1]);
            const int p1 = cvtpk_bf16(ev[2], ev[3]);
            const int p2 = cvtpk_bf16(ev[4], ev[5]);
            const int p3 = cvtpk_bf16(ev[6], ev[7]);
            auto s02 = __builtin_amdgcn_permlane32_swap(p0, p2, false, false);
            auto s13 = __builtin_amdgcn_permlane32_swap(p1, p3, false, false);
            union { int wd[4]; bf16x8 v; } pf;
            pf.wd[0] = s02[0]; pf.wd[1] = s13[0];
            pf.wd[2] = s02[1]; pf.wd[3] = s13[1];
            __builtin_amdgcn_s_setprio(1);
            O0 = __builtin_amdgcn_mfma_f32_32x32x16_bf16(pf.v, vf[0][kc], O0, 0, 0, 0);
            O1 = __builtin_amdgcn_mfma_f32_32x32x16_bf16(pf.v, vf[1][kc], O1, 0, 0, 0);
            __builtin_amdgcn_s_setprio(0);
        }
        t = tn;
    }

    // ---- publish per-wave partials.  O C-layout: row(q)=(rr&3)+8*(rr>>2)+4*hi,
    //      col(d) = l5 (+32 for O1).  Row-sum: lane-halves hold complementary
    //      key-halves for the same q -> one shfl_xor(32).
    const float lt = ls + __shfl_xor(ls, 32);
#pragma unroll
    for (int rr = 0; rr < 16; ++rr) {
        const int row = (rr & 3) + 8 * (rr >> 2) + 4 * hi;
        Obuf[w][row][l5]      = O0[rr];
        Obuf[w][row][32 + l5] = O1[rr];
    }
    if (lane < 32) lbuf[w][l5] = lt;
    __syncthreads();

    // ---- combine: plain sums over 8 k-split partials; coalesced store
    const int col = tid & 63;
    const int r0  = tid >> 6;
    for (int ii = 0; ii < 4; ++ii) {
        const int row = r0 + ii * 8;
        float o = 0.f, lsum = 0.f;
        for (int ww = 0; ww < 8; ++ww) {
            o    += Obuf[ww][row][col];
            lsum += lbuf[ww][row];
        }
        out[(b * S_LEN + q0 + row) * 64 + col] = o / lsum;
    }
}

// ---------------------------------------------------------------------------
extern "C" void kernel_launch(void* const* d_in, const int* in_sizes, int n_in,
                              void* d_out, int out_size, void* d_ws, size_t ws_size,
                              hipStream_t stream) {
    const float* x  = (const float*)d_in[0];
    const float* Wq = (const float*)d_in[1];
    const float* bq = (const float*)d_in[2];
    const float* Wk = (const float*)d_in[3];
    const float* bk = (const float*)d_in[4];
    const float* Wv = (const float*)d_in[5];
    const float* bv = (const float*)d_in[6];
    float* out = (float*)d_out;

    unsigned short* wt = (unsigned short*)d_ws;   // 16 chunks x 12288 shorts
    unsigned short* Qp = wt + 196608;             // 16384*64 each
    unsigned short* Kp = Qp + 1048576;
    unsigned short* Vt = Kp + 1048576;            // [b][64][4096]

    hipLaunchKernelGGL(wprep_kernel, dim3(48), dim3(256), 0, stream, Wq, Wk, Wv, wt);
    hipLaunchKernelGGL(qkv_kernel, dim3(256), dim3(512), 0, stream,
                       x, wt, bq, bk, bv, Qp, Kp, Vt);
    hipLaunchKernelGGL(flash_kernel, dim3(512), dim3(512), 0, stream,
                       Qp, Kp, Vt, out);
}

// Round 3
// 152.354 us; speedup vs baseline: 1.0854x; 1.0053x over previous
//
#include <hip/hip_runtime.h>
#include <stdint.h>

#define S_LEN 4096
#define EMB   1024
#define HEAD  64

typedef short bf16x8 __attribute__((ext_vector_type(8)));
typedef float f32x4  __attribute__((ext_vector_type(4)));
typedef float f32x16 __attribute__((ext_vector_type(16)));
typedef unsigned short ushort8 __attribute__((ext_vector_type(8)));

// scale = 1/sqrt(64) = 0.125, folded with log2(e) so softmax uses exp2
#define QSCALE 0.18033688011112042f

__device__ __forceinline__ unsigned short f2bf(float f) {
    union { float f; uint32_t u; } v; v.f = f;
    uint32_t r = v.u + 0x7fffu + ((v.u >> 16) & 1u);
    return (unsigned short)(r >> 16);
}

// pack two f32 -> one u32 of 2x bf16 (RNE), gfx950 HW op (no builtin)
__device__ __forceinline__ int cvtpk_bf16(float lo, float hi_) {
    int r;
    asm("v_cvt_pk_bf16_f32 %0, %1, %2" : "=v"(r) : "v"(lo), "v"(hi_));
    return r;
}

// async global->LDS, 16B per lane.  LDS dest is wave-uniform base + lane*16;
// global src is per-lane (m104).  size must be a literal.
__device__ __forceinline__ void gload_lds16(const void* g, void* l) {
    __builtin_amdgcn_global_load_lds(
        (const __attribute__((address_space(1))) void*)g,
        (__attribute__((address_space(3))) void*)l, 16, 0, 0);
}

// ---------------------------------------------------------------------------
// Kernel 0: W prep.  Writes wt as 16 per-kchunk LINEAR LDS IMAGES of
// 192 rows x 128 B, XOR-swizzled (chunk ^= row&7 on 16B chunks) so qkv can
// stage it with global_load_lds (linear dest) and read with swizzled
// ds_read_b128 conflict-free (rule #21: pre-swizzled source + swizzled read).
// ---------------------------------------------------------------------------
__global__ void wprep_kernel(const float* __restrict__ Wq,
                             const float* __restrict__ Wk,
                             const float* __restrict__ Wv,
                             unsigned short* __restrict__ wt) {
    __shared__ float t[64][65];
    const int tid = threadIdx.x;
    const int m   = blockIdx.x >> 4;
    const int kcb = blockIdx.x & 15;
    const int k0  = kcb << 6;
    const float* W = (m == 0) ? Wq : (m == 1) ? Wk : Wv;
    for (int i = 0; i < 4; ++i) {
        const int k  = (tid >> 4) + i * 16;
        const int n4 = (tid & 15) << 2;
        float4 v = *(const float4*)&W[(k0 + k) * 64 + n4];
        t[k][n4 + 0] = v.x; t[k][n4 + 1] = v.y;
        t[k][n4 + 2] = v.z; t[k][n4 + 3] = v.w;
    }
    __syncthreads();
    const int n = tid >> 2, kq = (tid & 3) << 4;   // 16 k-values per thread
    __align__(16) unsigned short u[16];
    for (int i = 0; i < 16; ++i) u[i] = f2bf(t[kq + i][n]);
    const int nimg = m * 64 + n;
    const int base = kcb * 12288 + nimg * 64;      // shorts
    const int c0   = (kq >> 3) ^ (n & 7);          // swizzled 16B-chunk idx
    const int c1   = ((kq >> 3) + 1) ^ (n & 7);
    *(int4*)&wt[base + c0 * 8] = *(int4*)&u[0];
    *(int4*)&wt[base + c1 * 8] = *(int4*)&u[8];
}

// ---------------------------------------------------------------------------
// Kernel 1: fused QKV projection, bf16 MFMA GEMM (unchanged from R2).
//   M=16384, K=1024, N=192.  256 blocks x 64-row tiles, 512 thr, BK=64.
//   W tile staged via global_load_lds from the pre-swizzled wt image; x tile
//   reg-staged with fp32->bf16 convert into a 72-padded buffer.
// ---------------------------------------------------------------------------
__global__ __launch_bounds__(512, 2) void qkv_kernel(
    const float* __restrict__ x, const unsigned short* __restrict__ wt,
    const float* __restrict__ bq, const float* __restrict__ bk,
    const float* __restrict__ bv,
    unsigned short* __restrict__ Qp, unsigned short* __restrict__ Kp,
    unsigned short* __restrict__ Vt) {

    __shared__ __align__(16) unsigned short xs[2][64 * 72];   // 18.4 KB
    __shared__ __align__(16) unsigned short ws[2][12288];     // 49.2 KB

    const int tid  = threadIdx.x;
    const int lane = tid & 63;
    const int w    = tid >> 6;        // 0..7
    const int wm   = w & 3;           // 0..3  (16-row quarter)
    const int wn   = w >> 2;          // 0..1  (96-col half)
    const int quad = lane >> 4;
    const int lid  = lane & 15;
    const int row0 = blockIdx.x * 64;

    f32x4 acc[6];
    for (int j = 0; j < 6; ++j) acc[j] = (f32x4){0.f, 0.f, 0.f, 0.f};

#define STAGE(BUF, KC)                                                         \
    do {                                                                       \
        {   /* x: 64 rows x 64 k fp32 -> bf16, 8 floats per thread */          \
            int rr = tid >> 3, c8 = (tid & 7) << 3;                            \
            const float* xp = &x[(row0 + rr) * EMB + (KC) * 64 + c8];          \
            float4 v0 = *(const float4*)xp;                                    \
            float4 v1 = *(const float4*)(xp + 4);                              \
            ushort8 u;                                                         \
            u[0] = f2bf(v0.x); u[1] = f2bf(v0.y);                              \
            u[2] = f2bf(v0.z); u[3] = f2bf(v0.w);                              \
            u[4] = f2bf(v1.x); u[5] = f2bf(v1.y);                              \
            u[6] = f2bf(v1.z); u[7] = f2bf(v1.w);                              \
            *(ushort8*)&xs[BUF][rr * 72 + c8] = u;                             \
        }                                                                      \
        {   /* wt chunk: 24.6 KB linear swizzled image, 3 KB per wave */       \
            const unsigned short* gs = &wt[(KC) * 12288 + w * 1536 + lane * 8];\
            gload_lds16(gs,        &ws[BUF][w * 1536]);                        \
            gload_lds16(gs +  512, &ws[BUF][w * 1536 +  512]);                 \
            gload_lds16(gs + 1024, &ws[BUF][w * 1536 + 1024]);                 \
        }                                                                      \
    } while (0)

    STAGE(0, 0);
    __syncthreads();

    for (int kc = 0; kc < 16; ++kc) {
        const int cur = kc & 1;
        if (kc + 1 < 16) STAGE(cur ^ 1, kc + 1);
        for (int kk = 0; kk < 2; ++kk) {
            bf16x8 a = *(const bf16x8*)&xs[cur][(wm * 16 + lid) * 72 + kk * 32 + quad * 8];
            const int swz = ((((kk << 2) | quad) ^ (lid & 7)) << 3);
            for (int nt = 0; nt < 6; ++nt) {
                const int n = wn * 96 + nt * 16 + lid;
                bf16x8 bfr = *(const bf16x8*)&ws[cur][n * 64 + swz];
                acc[nt] = __builtin_amdgcn_mfma_f32_16x16x32_bf16(a, bfr, acc[nt], 0, 0, 0);
            }
        }
        __syncthreads();
    }
#undef STAGE

    for (int nt = 0; nt < 6; ++nt) {
        const int col = wn * 96 + nt * 16 + lid;
        const int mid = col >> 6;          // 0=Q 1=K 2=V, uniform per (wn,nt)
        const int lc  = col & 63;
        const float bias = (mid == 0) ? bq[lc] : (mid == 1) ? bk[lc] : bv[lc];
        const int rb = row0 + wm * 16 + quad * 4;   // + j
        f32x4 v = acc[nt];
        if (mid == 0) {
            for (int j = 0; j < 4; ++j)
                Qp[(rb + j) * 64 + lc] = f2bf((v[j] + bias) * QSCALE);
        } else if (mid == 1) {
            for (int j = 0; j < 4; ++j)
                Kp[(rb + j) * 64 + lc] = f2bf(v[j] + bias);
        } else {
            const int bb = rb >> 12, s = rb & 4095;  // rb%4==0 -> no straddle
            ushort4 u;
            u.x = f2bf(v[0] + bias); u.y = f2bf(v[1] + bias);
            u.z = f2bf(v[2] + bias); u.w = f2bf(v[3] + bias);
            *(ushort4*)&Vt[(bb * 64 + lc) * S_LEN + s] = u;
        }
    }
}

// ---------------------------------------------------------------------------
// Kernel 2: MFMA flash attention (causal), swapped-QK^T 32x32 structure.
//   THIS ROUND: assumption-free load balance + VGPR-cap lift.
//   - 256 blocks, each processes the complementary q-tile PAIR
//     (127-p, p) sequentially -> EXACTLY 129 k-tiles per block, identical
//     work regardless of how the CP maps blocks to CUs (the old scheme
//     needed slot-pairing (m, m+32) -> same CU, which was never verified;
//     R0's Occupancy=16% at a 50% config is a tail/imbalance signature).
//   - 256 blocks = 1 block/CU (grid-limited), so __launch_bounds__(512,1)
//     lifts the VGPR cap 128 -> 256 at zero occupancy cost: the 32x32
//     register set (~140 VGPR) was at/past the old cap's spill cliff.
//   - QK accumulation split into two independent 2-deep MFMA chains.
// ---------------------------------------------------------------------------
__global__ __launch_bounds__(512, 1) void flash_kernel(
    const unsigned short* __restrict__ Qp, const unsigned short* __restrict__ Kp,
    const unsigned short* __restrict__ Vt, float* __restrict__ out) {

    __shared__ __align__(16) float Obuf[8][32][66];   // 67.6 KB
    __shared__ float lbuf[8][32];                     // 1 KB

    const int tid  = threadIdx.x;
    const int lane = tid & 63;
    const int w    = tid >> 6;        // 0..7 (k-split index)
    const int hi   = lane >> 5;       // lane half (0/1)
    const int l5   = lane & 31;       // q-row within tile / d within half

    // 256 blocks: XCD = l&7 (batch pinned to XCD pair {b, b+4} for L2
    // locality), pair index p = (XCD>>2)*32 + (l>>3) in 0..63.
    const int l  = blockIdx.x;        // 0..255
    const int x  = l & 7;
    const int b  = x & 3;
    const int p  = ((x >> 2) << 5) + (l >> 3);

    const unsigned short* Kb = &Kp[b * S_LEN * 64];
    const unsigned short* Vb = &Vt[b * 64 * S_LEN];

    for (int half = 0; half < 2; ++half) {
        const int qt = half ? p : 127 - p;
        const int q0 = qt * 32;
        const int nt = qt + 1;        // 32-wide k tiles

        // Q as B-frags: B[d][q], lane holds Q[q=l5][d-chunk]
        bf16x8 qf[4];
#pragma unroll
        for (int dk = 0; dk < 4; ++dk)
            qf[dk] = *(const bf16x8*)&Qp[(b * S_LEN + q0 + l5) * 64 + dk * 16 + hi * 8];

        f32x16 O0 = {}, O1 = {};      // O[q][d], d-halves 0..31 / 32..63
        float ls = 0.f;               // row-sum partial (q = l5, own key-half)

        // prologue: K A-frags for first tile
        int t = w;
        bf16x8 kf[4];
        if (t < nt) {
#pragma unroll
            for (int dk = 0; dk < 4; ++dk)
                kf[dk] = *(const bf16x8*)&Kb[(t * 32 + l5) * 64 + dk * 16 + hi * 8];
        }

        while (t < nt) {
            const int kt = t << 5;
            // ---- V B-frags for this tile: B[key][d]
            bf16x8 vf[2][2];
#pragma unroll
            for (int dh = 0; dh < 2; ++dh)
#pragma unroll
                for (int kc = 0; kc < 2; ++kc)
                    vf[dh][kc] = *(const bf16x8*)&Vb[(dh * 32 + l5) * S_LEN + kt + kc * 16 + hi * 8];

            // ---- swapped QK^T, two independent 2-deep chains:
            //      st[rr] = S^T[key][q], key = kt+(rr&3)+8*(rr>>2)+4*hi, q = q0+l5
            __builtin_amdgcn_s_setprio(1);
            f32x16 sa = {}, sb = {};
            sa = __builtin_amdgcn_mfma_f32_32x32x16_bf16(kf[0], qf[0], sa, 0, 0, 0);
            sb = __builtin_amdgcn_mfma_f32_32x32x16_bf16(kf[1], qf[1], sb, 0, 0, 0);
            sa = __builtin_amdgcn_mfma_f32_32x32x16_bf16(kf[2], qf[2], sa, 0, 0, 0);
            sb = __builtin_amdgcn_mfma_f32_32x32x16_bf16(kf[3], qf[3], sb, 0, 0, 0);
            __builtin_amdgcn_s_setprio(0);

            // ---- prefetch K(t+8) (hidden under softmax + PV)
            const int tn = t + 8;
            if (tn < nt) {
#pragma unroll
                for (int dk = 0; dk < 4; ++dk)
                    kf[dk] = *(const bf16x8*)&Kb[(tn * 32 + l5) * 64 + dk * 16 + hi * 8];
            }

            f32x16 st = sa + sb;

            // ---- causal mask (diagonal tile only)
            if (t == nt - 1) {
#pragma unroll
                for (int rr = 0; rr < 16; ++rr) {
                    const int key = kt + (rr & 3) + 8 * (rr >> 2) + 4 * hi;
                    if (key > q0 + l5) st[rr] = -1e30f;
                }
            }

            // ---- exp2 + in-register P->bf16 A-frag (T12), fused with PV
#pragma unroll
            for (int kc = 0; kc < 2; ++kc) {
                const int c8 = kc * 8;
                float ev[8];
#pragma unroll
                for (int i = 0; i < 8; ++i) ev[i] = __builtin_amdgcn_exp2f(st[c8 + i]);
                ls += ((ev[0] + ev[1]) + (ev[2] + ev[3])) +
                      ((ev[4] + ev[5]) + (ev[6] + ev[7]));
                const int p0 = cvtpk_bf16(ev[0], ev[1]);
                const int p1 = cvtpk_bf16(ev[2], ev[3]);
                const int p2 = cvtpk_bf16(ev[4], ev[5]);
                const int p3 = cvtpk_bf16(ev[6], ev[7]);
                auto s02 = __builtin_amdgcn_permlane32_swap(p0, p2, false, false);
                auto s13 = __builtin_amdgcn_permlane32_swap(p1, p3, false, false);
                union { int wd[4]; bf16x8 v; } pf;
                pf.wd[0] = s02[0]; pf.wd[1] = s13[0];
                pf.wd[2] = s02[1]; pf.wd[3] = s13[1];
                __builtin_amdgcn_s_setprio(1);
                O0 = __builtin_amdgcn_mfma_f32_32x32x16_bf16(pf.v, vf[0][kc], O0, 0, 0, 0);
                O1 = __builtin_amdgcn_mfma_f32_32x32x16_bf16(pf.v, vf[1][kc], O1, 0, 0, 0);
                __builtin_amdgcn_s_setprio(0);
            }
            t = tn;
        }

        // ---- publish per-wave partials.  O C-layout: row(q)=(rr&3)+8*(rr>>2)+4*hi,
        //      col(d) = l5 (+32 for O1).  Lane-halves hold complementary
        //      key-halves for the same q -> one shfl_xor(32) for the row-sum.
        const float lt = ls + __shfl_xor(ls, 32);
#pragma unroll
        for (int rr = 0; rr < 16; ++rr) {
            const int row = (rr & 3) + 8 * (rr >> 2) + 4 * hi;
            Obuf[w][row][l5]      = O0[rr];
            Obuf[w][row][32 + l5] = O1[rr];
        }
        if (lane < 32) lbuf[w][l5] = lt;
        __syncthreads();

        // ---- combine: plain sums over 8 k-split partials; coalesced store
        const int col = tid & 63;
        const int r0  = tid >> 6;
        for (int ii = 0; ii < 4; ++ii) {
            const int row = r0 + ii * 8;
            float o = 0.f, lsum = 0.f;
            for (int ww = 0; ww < 8; ++ww) {
                o    += Obuf[ww][row][col];
                lsum += lbuf[ww][row];
            }
            out[(b * S_LEN + q0 + row) * 64 + col] = o / lsum;
        }
        __syncthreads();   // combine reads done before next half's publish
    }
}

// ---------------------------------------------------------------------------
extern "C" void kernel_launch(void* const* d_in, const int* in_sizes, int n_in,
                              void* d_out, int out_size, void* d_ws, size_t ws_size,
                              hipStream_t stream) {
    const float* x  = (const float*)d_in[0];
    const float* Wq = (const float*)d_in[1];
    const float* bq = (const float*)d_in[2];
    const float* Wk = (const float*)d_in[3];
    const float* bk = (const float*)d_in[4];
    const float* Wv = (const float*)d_in[5];
    const float* bv = (const float*)d_in[6];
    float* out = (float*)d_out;

    unsigned short* wt = (unsigned short*)d_ws;   // 16 chunks x 12288 shorts
    unsigned short* Qp = wt + 196608;             // 16384*64 each
    unsigned short* Kp = Qp + 1048576;
    unsigned short* Vt = Kp + 1048576;            // [b][64][4096]

    hipLaunchKernelGGL(wprep_kernel, dim3(48), dim3(256), 0, stream, Wq, Wk, Wv, wt);
    hipLaunchKernelGGL(qkv_kernel, dim3(256), dim3(512), 0, stream,
                       x, wt, bq, bk, bv, Qp, Kp, Vt);
    hipLaunchKernelGGL(flash_kernel, dim3(256), dim3(512), 0, stream,
                       Qp, Kp, Vt, out);
}

// Round 4
// 133.032 us; speedup vs baseline: 1.2430x; 1.1452x over previous
//
#include <hip/hip_runtime.h>
#include <stdint.h>

#define S_LEN 4096
#define EMB   1024
#define HEAD  64

typedef short bf16x8 __attribute__((ext_vector_type(8)));
typedef float f32x4  __attribute__((ext_vector_type(4)));
typedef float f32x16 __attribute__((ext_vector_type(16)));
typedef unsigned short ushort8 __attribute__((ext_vector_type(8)));

// scale = 1/sqrt(64) = 0.125, folded with log2(e) so softmax uses exp2
#define QSCALE 0.18033688011112042f

__device__ __forceinline__ unsigned short f2bf(float f) {
    union { float f; uint32_t u; } v; v.f = f;
    uint32_t r = v.u + 0x7fffu + ((v.u >> 16) & 1u);
    return (unsigned short)(r >> 16);
}

// pack two f32 -> one u32 of 2x bf16 (RNE), gfx950 HW op (no builtin)
__device__ __forceinline__ int cvtpk_bf16(float lo, float hi_) {
    int r;
    asm("v_cvt_pk_bf16_f32 %0, %1, %2" : "=v"(r) : "v"(lo), "v"(hi_));
    return r;
}

// async global->LDS, 16B per lane.  LDS dest is wave-uniform base + lane*16;
// global src is per-lane (m104).  size must be a literal.
__device__ __forceinline__ void gload_lds16(const void* g, void* l) {
    __builtin_amdgcn_global_load_lds(
        (const __attribute__((address_space(1))) void*)g,
        (__attribute__((address_space(3))) void*)l, 16, 0, 0);
}

// ---------------------------------------------------------------------------
// Fragment-blocked layouts (NEW this round):
//   Qp/Kp : [s/32][8 d-chunks][32 rows][8 d]   (2048 shorts per s-block)
//           elem(s,d) -> (s>>5)*2048 + (d>>3)*256 + (s&31)*8 + (d&7)
//   Vt    : [b][s/8][64 d][8 keys]             (512 shorts per s-group)
//           elem(b,s,d) -> b*262144 + (s>>3)*512 + d*8 + (s&7)
// Every flash-side fragment load becomes two dense 512B segments (16 fully
// used cache lines per instruction vs 32 half-used with row-major), which
// attacks the TA/line-serialization bottleneck that survived R1-R3.
// ---------------------------------------------------------------------------

// ---------------------------------------------------------------------------
// Kernel 0: W prep.  Writes wt as 16 per-kchunk LINEAR LDS IMAGES of
// 192 rows x 128 B, XOR-swizzled (chunk ^= row&7 on 16B chunks) so qkv can
// stage it with global_load_lds (linear dest) and read with swizzled
// ds_read_b128 conflict-free (rule #21).  (unchanged)
// ---------------------------------------------------------------------------
__global__ void wprep_kernel(const float* __restrict__ Wq,
                             const float* __restrict__ Wk,
                             const float* __restrict__ Wv,
                             unsigned short* __restrict__ wt) {
    __shared__ float t[64][65];
    const int tid = threadIdx.x;
    const int m   = blockIdx.x >> 4;
    const int kcb = blockIdx.x & 15;
    const int k0  = kcb << 6;
    const float* W = (m == 0) ? Wq : (m == 1) ? Wk : Wv;
    for (int i = 0; i < 4; ++i) {
        const int k  = (tid >> 4) + i * 16;
        const int n4 = (tid & 15) << 2;
        float4 v = *(const float4*)&W[(k0 + k) * 64 + n4];
        t[k][n4 + 0] = v.x; t[k][n4 + 1] = v.y;
        t[k][n4 + 2] = v.z; t[k][n4 + 3] = v.w;
    }
    __syncthreads();
    const int n = tid >> 2, kq = (tid & 3) << 4;   // 16 k-values per thread
    __align__(16) unsigned short u[16];
    for (int i = 0; i < 16; ++i) u[i] = f2bf(t[kq + i][n]);
    const int nimg = m * 64 + n;
    const int base = kcb * 12288 + nimg * 64;      // shorts
    const int c0   = (kq >> 3) ^ (n & 7);          // swizzled 16B-chunk idx
    const int c1   = ((kq >> 3) + 1) ^ (n & 7);
    *(int4*)&wt[base + c0 * 8] = *(int4*)&u[0];
    *(int4*)&wt[base + c1 * 8] = *(int4*)&u[8];
}

// ---------------------------------------------------------------------------
// Kernel 1: fused QKV projection, bf16 MFMA GEMM.  Main loop unchanged from
// R2; epilogue now writes the fragment-blocked Qp/Kp/Vt layouts.
// ---------------------------------------------------------------------------
__global__ __launch_bounds__(512, 2) void qkv_kernel(
    const float* __restrict__ x, const unsigned short* __restrict__ wt,
    const float* __restrict__ bq, const float* __restrict__ bk,
    const float* __restrict__ bv,
    unsigned short* __restrict__ Qp, unsigned short* __restrict__ Kp,
    unsigned short* __restrict__ Vt) {

    __shared__ __align__(16) unsigned short xs[2][64 * 72];   // 18.4 KB
    __shared__ __align__(16) unsigned short ws[2][12288];     // 49.2 KB

    const int tid  = threadIdx.x;
    const int lane = tid & 63;
    const int w    = tid >> 6;        // 0..7
    const int wm   = w & 3;           // 0..3  (16-row quarter)
    const int wn   = w >> 2;          // 0..1  (96-col half)
    const int quad = lane >> 4;
    const int lid  = lane & 15;
    const int row0 = blockIdx.x * 64;

    f32x4 acc[6];
    for (int j = 0; j < 6; ++j) acc[j] = (f32x4){0.f, 0.f, 0.f, 0.f};

#define STAGE(BUF, KC)                                                         \
    do {                                                                       \
        {   /* x: 64 rows x 64 k fp32 -> bf16, 8 floats per thread */          \
            int rr = tid >> 3, c8 = (tid & 7) << 3;                            \
            const float* xp = &x[(row0 + rr) * EMB + (KC) * 64 + c8];          \
            float4 v0 = *(const float4*)xp;                                    \
            float4 v1 = *(const float4*)(xp + 4);                              \
            ushort8 u;                                                         \
            u[0] = f2bf(v0.x); u[1] = f2bf(v0.y);                              \
            u[2] = f2bf(v0.z); u[3] = f2bf(v0.w);                              \
            u[4] = f2bf(v1.x); u[5] = f2bf(v1.y);                              \
            u[6] = f2bf(v1.z); u[7] = f2bf(v1.w);                              \
            *(ushort8*)&xs[BUF][rr * 72 + c8] = u;                             \
        }                                                                      \
        {   /* wt chunk: 24.6 KB linear swizzled image, 3 KB per wave */       \
            const unsigned short* gs = &wt[(KC) * 12288 + w * 1536 + lane * 8];\
            gload_lds16(gs,        &ws[BUF][w * 1536]);                        \
            gload_lds16(gs +  512, &ws[BUF][w * 1536 +  512]);                 \
            gload_lds16(gs + 1024, &ws[BUF][w * 1536 + 1024]);                 \
        }                                                                      \
    } while (0)

    STAGE(0, 0);
    __syncthreads();

    for (int kc = 0; kc < 16; ++kc) {
        const int cur = kc & 1;
        if (kc + 1 < 16) STAGE(cur ^ 1, kc + 1);
        for (int kk = 0; kk < 2; ++kk) {
            bf16x8 a = *(const bf16x8*)&xs[cur][(wm * 16 + lid) * 72 + kk * 32 + quad * 8];
            const int swz = ((((kk << 2) | quad) ^ (lid & 7)) << 3);
            for (int nt = 0; nt < 6; ++nt) {
                const int n = wn * 96 + nt * 16 + lid;
                bf16x8 bfr = *(const bf16x8*)&ws[cur][n * 64 + swz];
                acc[nt] = __builtin_amdgcn_mfma_f32_16x16x32_bf16(a, bfr, acc[nt], 0, 0, 0);
            }
        }
        __syncthreads();
    }
#undef STAGE

    for (int nt = 0; nt < 6; ++nt) {
        const int col = wn * 96 + nt * 16 + lid;
        const int mid = col >> 6;          // 0=Q 1=K 2=V, uniform per (wn,nt)
        const int lc  = col & 63;
        const float bias = (mid == 0) ? bq[lc] : (mid == 1) ? bk[lc] : bv[lc];
        const int rb = row0 + wm * 16 + quad * 4;   // + j
        f32x4 v = acc[nt];
        if (mid < 2) {
            // frag-blocked Q/K: (s>>5)*2048 + (lc>>3)*256 + (s&31)*8 + (lc&7)
            const int base = ((rb >> 5) << 11) + ((lc >> 3) << 8)
                           + ((rb & 31) << 3) + (lc & 7);
            unsigned short* P = (mid == 0) ? Qp : Kp;
            const float sc = (mid == 0) ? QSCALE : 1.0f;
            for (int j = 0; j < 4; ++j)
                P[base + j * 8] = f2bf((v[j] + bias) * sc);
        } else {
            // frag-blocked V: b*262144 + (s>>3)*512 + d*8 + (s&7); rb%4==0
            const int bb = rb >> 12, s = rb & 4095;
            ushort4 u;
            u.x = f2bf(v[0] + bias); u.y = f2bf(v[1] + bias);
            u.z = f2bf(v[2] + bias); u.w = f2bf(v[3] + bias);
            *(ushort4*)&Vt[bb * 262144 + (s >> 3) * 512 + lc * 8 + (s & 7)] = u;
        }
    }
}

// ---------------------------------------------------------------------------
// Kernel 2: MFMA flash attention (causal), swapped-QK^T 32x32 structure.
//   THIS ROUND: all Q/K/V fragment loads read the fragment-blocked layouts
//   -> every global load is two dense 512B segments (100% line utilization,
//   16 lines/instr vs 32 half-used).  Register contents per lane identical
//   to R3, so MFMA/softmax/mask/combine logic is unchanged.
//   Balance: paired q-tiles (127-p, p) per block, exactly 129 k-tiles each.
// ---------------------------------------------------------------------------
__global__ __launch_bounds__(512, 1) void flash_kernel(
    const unsigned short* __restrict__ Qp, const unsigned short* __restrict__ Kp,
    const unsigned short* __restrict__ Vt, float* __restrict__ out) {

    __shared__ __align__(16) float Obuf[8][32][66];   // 67.6 KB
    __shared__ float lbuf[8][32];                     // 1 KB

    const int tid  = threadIdx.x;
    const int lane = tid & 63;
    const int w    = tid >> 6;        // 0..7 (k-split index)
    const int hi   = lane >> 5;       // lane half (0/1)
    const int l5   = lane & 31;       // q-row within tile / d within half

    // 256 blocks: XCD = l&7 (batch pinned to XCD pair {b, b+4} for L2
    // locality), pair index p = (XCD>>2)*32 + (l>>3) in 0..63.
    const int l  = blockIdx.x;        // 0..255
    const int x  = l & 7;
    const int b  = x & 3;
    const int p  = ((x >> 2) << 5) + (l >> 3);

    const unsigned short* Kb = &Kp[b * 262144];   // b*128 s-blocks * 2048
    const unsigned short* Vb = &Vt[b * 262144];

    for (int half = 0; half < 2; ++half) {
        const int qt = half ? p : 127 - p;
        const int q0 = qt * 32;
        const int nt = qt + 1;        // 32-wide k tiles

        // Q as B-frags: lane l5 = q-row, 8 consecutive d per reg (dense load)
        bf16x8 qf[4];
#pragma unroll
        for (int dk = 0; dk < 4; ++dk)
            qf[dk] = *(const bf16x8*)&Qp[((b << 7) + qt) * 2048
                                         + (dk * 2 + hi) * 256 + l5 * 8];

        f32x16 O0 = {}, O1 = {};      // O[q][d], d-halves 0..31 / 32..63
        float ls = 0.f;               // row-sum partial (q = l5, own key-half)

        // prologue: K A-frags for first tile (dense)
        int t = w;
        bf16x8 kf[4];
        if (t < nt) {
#pragma unroll
            for (int dk = 0; dk < 4; ++dk)
                kf[dk] = *(const bf16x8*)&Kb[t * 2048 + (dk * 2 + hi) * 256 + l5 * 8];
        }

        while (t < nt) {
            const int kt = t << 5;
            // ---- V B-frags for this tile (dense): lane l5 = d, 8 keys/reg
            bf16x8 vf[2][2];
#pragma unroll
            for (int kc = 0; kc < 2; ++kc)
#pragma unroll
                for (int dh = 0; dh < 2; ++dh)
                    vf[dh][kc] = *(const bf16x8*)&Vb[(t * 4 + kc * 2 + hi) * 512
                                                     + (dh * 32 + l5) * 8];

            // ---- swapped QK^T, two independent 2-deep chains:
            //      st[rr] = S^T[key][q], key = kt+(rr&3)+8*(rr>>2)+4*hi, q = q0+l5
            __builtin_amdgcn_s_setprio(1);
            f32x16 sa = {}, sb = {};
            sa = __builtin_amdgcn_mfma_f32_32x32x16_bf16(kf[0], qf[0], sa, 0, 0, 0);
            sb = __builtin_amdgcn_mfma_f32_32x32x16_bf16(kf[1], qf[1], sb, 0, 0, 0);
            sa = __builtin_amdgcn_mfma_f32_32x32x16_bf16(kf[2], qf[2], sa, 0, 0, 0);
            sb = __builtin_amdgcn_mfma_f32_32x32x16_bf16(kf[3], qf[3], sb, 0, 0, 0);
            __builtin_amdgcn_s_setprio(0);

            // ---- prefetch K(t+8) (dense; hidden under softmax + PV)
            const int tn = t + 8;
            if (tn < nt) {
#pragma unroll
                for (int dk = 0; dk < 4; ++dk)
                    kf[dk] = *(const bf16x8*)&Kb[tn * 2048 + (dk * 2 + hi) * 256 + l5 * 8];
            }

            f32x16 st = sa + sb;

            // ---- causal mask (diagonal tile only)
            if (t == nt - 1) {
#pragma unroll
                for (int rr = 0; rr < 16; ++rr) {
                    const int key = kt + (rr & 3) + 8 * (rr >> 2) + 4 * hi;
                    if (key > q0 + l5) st[rr] = -1e30f;
                }
            }

            // ---- exp2 + in-register P->bf16 A-frag (T12), fused with PV
#pragma unroll
            for (int kc = 0; kc < 2; ++kc) {
                const int c8 = kc * 8;
                float ev[8];
#pragma unroll
                for (int i = 0; i < 8; ++i) ev[i] = __builtin_amdgcn_exp2f(st[c8 + i]);
                ls += ((ev[0] + ev[1]) + (ev[2] + ev[3])) +
                      ((ev[4] + ev[5]) + (ev[6] + ev[7]));
                const int p0 = cvtpk_bf16(ev[0], ev[1]);
                const int p1 = cvtpk_bf16(ev[2], ev[3]);
                const int p2 = cvtpk_bf16(ev[4], ev[5]);
                const int p3 = cvtpk_bf16(ev[6], ev[7]);
                auto s02 = __builtin_amdgcn_permlane32_swap(p0, p2, false, false);
                auto s13 = __builtin_amdgcn_permlane32_swap(p1, p3, false, false);
                union { int wd[4]; bf16x8 v; } pf;
                pf.wd[0] = s02[0]; pf.wd[1] = s13[0];
                pf.wd[2] = s02[1]; pf.wd[3] = s13[1];
                __builtin_amdgcn_s_setprio(1);
                O0 = __builtin_amdgcn_mfma_f32_32x32x16_bf16(pf.v, vf[0][kc], O0, 0, 0, 0);
                O1 = __builtin_amdgcn_mfma_f32_32x32x16_bf16(pf.v, vf[1][kc], O1, 0, 0, 0);
                __builtin_amdgcn_s_setprio(0);
            }
            t = tn;
        }

        // ---- publish per-wave partials.  O C-layout: row(q)=(rr&3)+8*(rr>>2)+4*hi,
        //      col(d) = l5 (+32 for O1).  Lane-halves hold complementary
        //      key-halves for the same q -> one shfl_xor(32) for the row-sum.
        const float lt = ls + __shfl_xor(ls, 32);
#pragma unroll
        for (int rr = 0; rr < 16; ++rr) {
            const int row = (rr & 3) + 8 * (rr >> 2) + 4 * hi;
            Obuf[w][row][l5]      = O0[rr];
            Obuf[w][row][32 + l5] = O1[rr];
        }
        if (lane < 32) lbuf[w][l5] = lt;
        __syncthreads();

        // ---- combine: plain sums over 8 k-split partials; coalesced store
        const int col = tid & 63;
        const int r0  = tid >> 6;
        for (int ii = 0; ii < 4; ++ii) {
            const int row = r0 + ii * 8;
            float o = 0.f, lsum = 0.f;
            for (int ww = 0; ww < 8; ++ww) {
                o    += Obuf[ww][row][col];
                lsum += lbuf[ww][row];
            }
            out[(b * S_LEN + q0 + row) * 64 + col] = o / lsum;
        }
        __syncthreads();   // combine reads done before next half's publish
    }
}

// ---------------------------------------------------------------------------
extern "C" void kernel_launch(void* const* d_in, const int* in_sizes, int n_in,
                              void* d_out, int out_size, void* d_ws, size_t ws_size,
                              hipStream_t stream) {
    const float* x  = (const float*)d_in[0];
    const float* Wq = (const float*)d_in[1];
    const float* bq = (const float*)d_in[2];
    const float* Wk = (const float*)d_in[3];
    const float* bk = (const float*)d_in[4];
    const float* Wv = (const float*)d_in[5];
    const float* bv = (const float*)d_in[6];
    float* out = (float*)d_out;

    unsigned short* wt = (unsigned short*)d_ws;   // 16 chunks x 12288 shorts
    unsigned short* Qp = wt + 196608;             // 16384*64 each (blocked)
    unsigned short* Kp = Qp + 1048576;
    unsigned short* Vt = Kp + 1048576;            // [b][s/8][64][8] blocked

    hipLaunchKernelGGL(wprep_kernel, dim3(48), dim3(256), 0, stream, Wq, Wk, Wv, wt);
    hipLaunchKernelGGL(qkv_kernel, dim3(256), dim3(512), 0, stream,
                       x, wt, bq, bk, bv, Qp, Kp, Vt);
    hipLaunchKernelGGL(flash_kernel, dim3(256), dim3(512), 0, stream,
                       Qp, Kp, Vt, out);
}